// Round 3
// baseline (1433.237 us; speedup 1.0000x reference)
//
#include <hip/hip_runtime.h>
#include <cmath>

#define VOCAB 32000
#define EMB   256
#define HID   512
#define TLEN  513      // SEQ + 1
#define G4    2048     // 4*HID
#define NWG   32       // recurrence workgroups
#define SOS   1

typedef unsigned long long u64;

// ---------------------------------------------------------------------------
// Kernel A: Xg[t][r] = W_ih[r] . emb[tok_t] + b_ih[r] + b_hh[r]
// grid (33, 8), block 256. Block (bt,br): 16 timesteps x 256 gate rows.
// ---------------------------------------------------------------------------
__global__ __launch_bounds__(256) void precompute_gates(
    const int* __restrict__ seq, const float* __restrict__ emb,
    const float* __restrict__ W_ih, const float* __restrict__ b_ih,
    const float* __restrict__ b_hh, float* __restrict__ Xg)
{
    __shared__ __align__(16) float ebuf[16][EMB];
    const int bt = blockIdx.x;   // 0..32
    const int br = blockIdx.y;   // 0..7
    const int tid = threadIdx.x;

    for (int tt = 0; tt < 16; ++tt) {
        int t = bt * 16 + tt;
        if (t < TLEN) {
            int tok = (t == 0) ? SOS : seq[t - 1];
            ebuf[tt][tid] = emb[(size_t)tok * EMB + tid];
        }
    }
    __syncthreads();

    const int row = br * 256 + tid;
    float acc[16];
#pragma unroll
    for (int tt = 0; tt < 16; ++tt) acc[tt] = 0.f;

    const float4* wp = (const float4*)(W_ih + (size_t)row * EMB);
#pragma unroll 4
    for (int k4 = 0; k4 < EMB / 4; ++k4) {
        float4 w = wp[k4];
#pragma unroll
        for (int tt = 0; tt < 16; ++tt) {
            float4 e = *(const float4*)&ebuf[tt][k4 * 4];
            acc[tt] = fmaf(w.x, e.x, fmaf(w.y, e.y, fmaf(w.z, e.z, fmaf(w.w, e.w, acc[tt]))));
        }
    }

    const float bias = b_ih[row] + b_hh[row];
    for (int tt = 0; tt < 16; ++tt) {
        int t = bt * 16 + tt;
        if (t < TLEN) Xg[(size_t)t * G4 + row] = acc[tt] + bias;
    }
}

// ---------------------------------------------------------------------------
// Kernel B: persistent LSTM recurrence. 32 WGs x 256 threads.
// Thread layout: wave w = gate q (i,f,g,o); lane l: seg = l>>4 (k quarter),
// sub = l&15 (j). Thread holds W_hh[row = q*512 + wg*16 + j][seg*128 .. +128)
// in 32 float4 registers. Per step:
//   poll (2 words, concurrently) -> hbuf -> barrier -> matvec ->
//   shfl_xor(16,32) k-reduce in-wave -> gbuf (seg0 lanes) -> barrier ->
//   activation (16 lanes) -> publish tag|h word (agent-scope relaxed atomic).
// Tag+payload share one 8B word => no fences needed (single-copy atomic).
// ---------------------------------------------------------------------------
__global__ __launch_bounds__(256, 1) void lstm_recurrence(
    const float* __restrict__ Xg, const float* __restrict__ W_hh,
    const float* __restrict__ h0, const float* __restrict__ c0,
    float* __restrict__ hs, u64* pk,
    float* __restrict__ out_hT, float* __restrict__ out_cT)
{
    __shared__ __align__(16) float hbuf[HID];
    __shared__ float gbuf[64];

    const int wg  = blockIdx.x;     // 0..31
    const int tid = threadIdx.x;
    const int w   = tid >> 6;       // wave = gate q
    const int l   = tid & 63;
    const int seg = l >> 4;         // k segment 0..3
    const int sub = l & 15;         // j within the 16-chunk
    const int row = w * HID + wg * 16 + sub;   // W_hh row

    // W_hh slice -> registers
    float4 wreg[32];
    const float4* wp = (const float4*)(W_hh + (size_t)row * HID + seg * 128);
#pragma unroll
    for (int i = 0; i < 32; ++i) wreg[i] = wp[i];

    float c = (tid < 16) ? c0[wg * 16 + tid] : 0.f;

    // h_{-1} = h0
    {
        float2 h2 = *(const float2*)&h0[tid * 2];
        hbuf[tid * 2]     = h2.x;
        hbuf[tid * 2 + 1] = h2.y;
    }
    __syncthreads();

    for (int t = 0; t < TLEN; ++t) {
        // Xg for this thread's row (only seg==0 lanes need it; coalesced 64B/wave)
        float xg = 0.f;
        if (seg == 0) xg = Xg[(size_t)t * G4 + row];

        if (t > 0) {
            const size_t base = (size_t)(t & 1) * HID;
            u64 w0 = 0, w1 = 0;
            bool ok0 = false, ok1 = false;
            do {
                if (!ok0) {
                    w0 = __hip_atomic_load(&pk[base + 2 * tid],
                                           __ATOMIC_RELAXED, __HIP_MEMORY_SCOPE_AGENT);
                    ok0 = (unsigned)(w0 >> 32) == (unsigned)t;
                }
                if (!ok1) {
                    w1 = __hip_atomic_load(&pk[base + 2 * tid + 1],
                                           __ATOMIC_RELAXED, __HIP_MEMORY_SCOPE_AGENT);
                    ok1 = (unsigned)(w1 >> 32) == (unsigned)t;
                }
            } while (!(ok0 && ok1));
            union { unsigned u; float f; } ua, ub;
            ua.u = (unsigned)w0;
            ub.u = (unsigned)w1;
            hbuf[2 * tid]     = ua.f;
            hbuf[2 * tid + 1] = ub.f;
            __syncthreads();
        }

        // partial matvec over my k quarter; hbuf reads are 16-lane broadcasts
        float acc8[8];
#pragma unroll
        for (int i = 0; i < 8; ++i) acc8[i] = 0.f;
#pragma unroll
        for (int i = 0; i < 32; ++i) {
            float4 wv = wreg[i];
            float4 h4 = *(const float4*)&hbuf[seg * 128 + i * 4];
            acc8[i & 7] = fmaf(wv.x, h4.x, fmaf(wv.y, h4.y,
                          fmaf(wv.z, h4.z, fmaf(wv.w, h4.w, acc8[i & 7]))));
        }
        float p = ((acc8[0] + acc8[1]) + (acc8[2] + acc8[3]))
                + ((acc8[4] + acc8[5]) + (acc8[6] + acc8[7]));

        // reduce over the 4 k-segments (lanes seg*16+sub within this wave)
        p += __shfl_xor(p, 16, 64);
        p += __shfl_xor(p, 32, 64);

        if (seg == 0) gbuf[w * 16 + sub] = p + xg;
        __syncthreads();

        if (tid < 16) {
            float gi = gbuf[tid], gf = gbuf[16 + tid], gg = gbuf[32 + tid], go = gbuf[48 + tid];
            float i_ = 1.f / (1.f + expf(-gi));
            float f_ = 1.f / (1.f + expf(-gf));
            float g_ = tanhf(gg);
            float o_ = 1.f / (1.f + expf(-go));
            c = fmaf(f_, c, i_ * g_);
            float h_ = o_ * tanhf(c);
            hs[(size_t)t * HID + wg * 16 + tid] = h_;   // for out_gemm
            if (t < TLEN - 1) {
                union { float f; unsigned u; } hv; hv.f = h_;
                u64 word = ((u64)(unsigned)(t + 1) << 32) | (u64)hv.u;
                __hip_atomic_store(&pk[((t + 1) & 1) * HID + wg * 16 + tid], word,
                                   __ATOMIC_RELAXED, __HIP_MEMORY_SCOPE_AGENT);
            } else {
                out_hT[wg * 16 + tid] = h_;
                out_cT[wg * 16 + tid] = c;
            }
        }
        // No trailing barrier needed: hbuf reads of step t complete before the
        // gbuf barrier; gbuf is re-written only after the next hbuf barrier,
        // which the activation lanes must also reach.
    }
}

// ---------------------------------------------------------------------------
// Kernel C: out[t][v] = hs[t] . W_out[v] + b_out[v]   (fp32 GEMM, B^T input)
// 128x128 tile, BK=32, 8x8 register tile, 256 threads. grid (5, 250):
// tb is the fast grid dim so the 5 blocks sharing a W_out panel are
// dispatch-adjacent (L2 reuse). Inner loop reads float4 along k
// (ds_read_b128: a-reads 4-addr broadcast, b-reads 2-way = conflict-free).
// ---------------------------------------------------------------------------
#define BM 128
#define BN 128
#define BK 32
#define LDT (BK + 4)   // 36: float4-aligned pad

__global__ __launch_bounds__(256) void out_gemm(
    const float* __restrict__ hs, const float* __restrict__ W_out,
    const float* __restrict__ b_out, float* __restrict__ out)
{
    __shared__ __align__(16) float As[BM][LDT];
    __shared__ __align__(16) float Bs[BN][LDT];

    const int tb = blockIdx.x;     // 0..4   (time tiles; fast dim)
    const int vb = blockIdx.y;     // 0..249 (vocab tiles)
    const int tid = threadIdx.x;
    const int tx = tid & 15;       // n group
    const int ty = tid >> 4;       // m group

    const int m0 = tb * BM, n0 = vb * BN;
    float acc[8][8];
#pragma unroll
    for (int i = 0; i < 8; ++i)
#pragma unroll
        for (int jj = 0; jj < 8; ++jj) acc[i][jj] = 0.f;

    for (int k0 = 0; k0 < HID; k0 += BK) {
#pragma unroll
        for (int it = 0; it < 4; ++it) {
            int li = tid + it * 256;        // 0..1023
            int m  = li >> 3;               // row 0..127
            int kq = li & 7;                // float4 index within BK
            int t  = m0 + m;
            float4 fa = (t < TLEN) ? *(const float4*)&hs[(size_t)t * HID + k0 + kq * 4]
                                   : make_float4(0.f, 0.f, 0.f, 0.f);
            *(float4*)&As[m][kq * 4] = fa;
            float4 fb = *(const float4*)&W_out[(size_t)(n0 + m) * HID + k0 + kq * 4];
            *(float4*)&Bs[m][kq * 4] = fb;
        }
        __syncthreads();

#pragma unroll
        for (int k4 = 0; k4 < BK / 4; ++k4) {
            float4 a4[8], b4[8];
#pragma unroll
            for (int i = 0; i < 8; ++i) a4[i] = *(const float4*)&As[ty + 16 * i][k4 * 4];
#pragma unroll
            for (int jj = 0; jj < 8; ++jj) b4[jj] = *(const float4*)&Bs[tx + 16 * jj][k4 * 4];
#pragma unroll
            for (int i = 0; i < 8; ++i)
#pragma unroll
                for (int jj = 0; jj < 8; ++jj) {
                    acc[i][jj] = fmaf(a4[i].x, b4[jj].x,
                                 fmaf(a4[i].y, b4[jj].y,
                                 fmaf(a4[i].z, b4[jj].z,
                                 fmaf(a4[i].w, b4[jj].w, acc[i][jj]))));
                }
        }
        __syncthreads();
    }

#pragma unroll
    for (int jj = 0; jj < 8; ++jj) {
        int v = n0 + tx + 16 * jj;
        float bo = b_out[v];
#pragma unroll
        for (int i = 0; i < 8; ++i) {
            int t = m0 + ty + 16 * i;
            if (t < TLEN) out[(size_t)t * VOCAB + v] = acc[i][jj] + bo;
        }
    }
}

// ---------------------------------------------------------------------------
extern "C" void kernel_launch(void* const* d_in, const int* in_sizes, int n_in,
                              void* d_out, int out_size, void* d_ws, size_t ws_size,
                              hipStream_t stream)
{
    const int*   seq   = (const int*)  d_in[0];
    const float* h0    = (const float*)d_in[1];
    const float* c0    = (const float*)d_in[2];
    const float* emb   = (const float*)d_in[3];
    const float* W_ih  = (const float*)d_in[4];
    const float* W_hh  = (const float*)d_in[5];
    const float* b_ih  = (const float*)d_in[6];
    const float* b_hh  = (const float*)d_in[7];
    const float* W_out = (const float*)d_in[8];
    const float* b_out = (const float*)d_in[9];

    float* out_logits = (float*)d_out;                      // [513][32000]
    float* out_hT     = out_logits + (size_t)TLEN * VOCAB;  // [512]
    float* out_cT     = out_hT + HID;                       // [512]

    float* Xg = (float*)d_ws;                    // 513*2048 floats
    float* hs = Xg + (size_t)TLEN * G4;          // 513*512 floats
    u64*   pk = (u64*)(hs + (size_t)TLEN * HID); // [2][512] packed tag|h words

    hipMemsetAsync(pk, 0, 2 * HID * sizeof(u64), stream);
    precompute_gates<<<dim3(33, 8), 256, 0, stream>>>(seq, emb, W_ih, b_ih, b_hh, Xg);
    lstm_recurrence<<<NWG, 256, 0, stream>>>(Xg, W_hh, h0, c0, hs, pk, out_hT, out_cT);
    out_gemm<<<dim3(5, 250), 256, 0, stream>>>(hs, W_out, b_out, out_logits);
}

// Round 5
// 1268.033 us; speedup vs baseline: 1.1303x; 1.1303x over previous
//
#include <hip/hip_runtime.h>
#include <cmath>

#define VOCAB 32000
#define EMB   256
#define HID   512
#define TLEN  513      // SEQ + 1
#define G4    2048     // 4*HID
#define NWG   32       // recurrence roles
#define GRID_LSTM 256  // launched WGs (XCD-0 gets ~32 via round-robin)
#define SOS   1

typedef unsigned long long u64;
typedef unsigned int uivec4 __attribute__((ext_vector_type(4)));

__device__ inline float fsig(float x)  { return __builtin_amdgcn_rcpf(1.f + __expf(-x)); }
__device__ inline float ftanh(float x) { return 1.f - 2.f * __builtin_amdgcn_rcpf(__expf(2.f * x) + 1.f); }

// ---------------------------------------------------------------------------
// Kernel A: Xg[t][r] = W_ih[r] . emb[tok_t] + b_ih[r] + b_hh[r]   (proven)
// ---------------------------------------------------------------------------
__global__ __launch_bounds__(256) void precompute_gates(
    const int* __restrict__ seq, const float* __restrict__ emb,
    const float* __restrict__ W_ih, const float* __restrict__ b_ih,
    const float* __restrict__ b_hh, float* __restrict__ Xg)
{
    __shared__ __align__(16) float ebuf[16][EMB];
    const int bt = blockIdx.x;   // 0..32
    const int br = blockIdx.y;   // 0..7
    const int tid = threadIdx.x;

    for (int tt = 0; tt < 16; ++tt) {
        int t = bt * 16 + tt;
        if (t < TLEN) {
            int tok = (t == 0) ? SOS : seq[t - 1];
            ebuf[tt][tid] = emb[(size_t)tok * EMB + tid];
        }
    }
    __syncthreads();

    const int row = br * 256 + tid;
    float acc[16];
#pragma unroll
    for (int tt = 0; tt < 16; ++tt) acc[tt] = 0.f;

    const float4* wp = (const float4*)(W_ih + (size_t)row * EMB);
#pragma unroll 4
    for (int k4 = 0; k4 < EMB / 4; ++k4) {
        float4 w = wp[k4];
#pragma unroll
        for (int tt = 0; tt < 16; ++tt) {
            float4 e = *(const float4*)&ebuf[tt][k4 * 4];
            acc[tt] = fmaf(w.x, e.x, fmaf(w.y, e.y, fmaf(w.z, e.z, fmaf(w.w, e.w, acc[tt]))));
        }
    }

    const float bias = b_ih[row] + b_hh[row];
    for (int tt = 0; tt < 16; ++tt) {
        int t = bt * 16 + tt;
        if (t < TLEN) Xg[(size_t)t * G4 + row] = acc[tt] + bias;
    }
}

// ---------------------------------------------------------------------------
// Kernel B: persistent LSTM recurrence (round-2 core + bounded fast path).
// Slow transport (always correct, proven): tag|float u64 words via agent-
// scope MALL loads/stores — now polled as ONE dwordx4 (one MALL RTT/iter).
// Fast transport (bounded, opportunistic): same words in pf[] via sc0
// stores/loads through the shared XCD L2 — used only if the 32 role WGs
// validate as same-XCD AND the t==1 vote confirms it actually works.
// Every new spin is bounded; the MALL loop guarantees progress.
// ---------------------------------------------------------------------------
__global__ __launch_bounds__(256, 1) void lstm_recurrence(
    const float* __restrict__ Xg, const float* __restrict__ W_hh,
    const float* __restrict__ h0, const float* __restrict__ c0,
    float* __restrict__ hs, u64* pk, u64* pf, u64* xrole, int* ctrs,
    float* __restrict__ out_hT, float* __restrict__ out_cT)
{
    __shared__ __align__(16) float hbuf[HID];
    __shared__ float pbuf[256];
    __shared__ int s_role, s_intra, s_usefast, svote[4];
    __shared__ unsigned sx[NWG];

    const int tid = threadIdx.x;

    // ---- role claim: single counter, XCD-0 priority, all claims bounded ----
    if (tid == 0) {
        unsigned xcc = 0x7f;
        asm volatile("s_getreg_b32 %0, hwreg(20, 0, 32)" : "=s"(xcc)); // HW_REG_XCC_ID
        xcc &= 0xffu;
        int role = -1;
        if (xcc == 0) {
            int r = __hip_atomic_fetch_add(&ctrs[0], 1, __ATOMIC_RELAXED, __HIP_MEMORY_SCOPE_AGENT);
            if (r < NWG) role = r;
        }
        if (role < 0) {
            for (int it = 0; it < 15000; ++it) {   // bounded ~1 ms priority window
                if (__hip_atomic_load(&ctrs[0], __ATOMIC_RELAXED, __HIP_MEMORY_SCOPE_AGENT) >= NWG) break;
                __builtin_amdgcn_s_sleep(2);
            }
            int r = __hip_atomic_fetch_add(&ctrs[0], 1, __ATOMIC_RELAXED, __HIP_MEMORY_SCOPE_AGENT);
            if (r < NWG) role = r;
        }
        if (role >= 0)
            __hip_atomic_store(&xrole[role], (1ull << 63) | (u64)xcc,
                               __ATOMIC_RELAXED, __HIP_MEMORY_SCOPE_AGENT);
        s_role = role;
    }
    __syncthreads();
    const int wg = s_role;
    if (wg < 0) return;   // 224 losers exit

    // ---- validation: are all 32 roles on one XCD? (poll terminates: all 32
    // role holders are live resident WGs that wrote xrole before any spin) ----
    if (tid < NWG) {
        u64 v;
        do { v = __hip_atomic_load(&xrole[tid], __ATOMIC_RELAXED, __HIP_MEMORY_SCOPE_AGENT); }
        while (!(v >> 63));
        sx[tid] = (unsigned)(v & 0xffu);
    }
    __syncthreads();
    if (tid == 0) {
        int eq = 1;
        for (int i = 1; i < NWG; ++i) eq &= (sx[i] == sx[0]);
        s_intra = eq;
        s_usefast = eq;
    }
    __syncthreads();
    const int intraflag = s_intra;

    // ---- round-2 compute layout ----
    const int wv  = tid >> 6;       // k segment 0..3 (one per wave)
    const int ln  = tid & 63;
    const int q   = ln >> 4;        // gate
    const int j   = ln & 15;
    const int row = q * HID + wg * 16 + j;

    float4 wreg[32];
    const float4* wp = (const float4*)(W_hh + (size_t)row * HID + wv * 128);
#pragma unroll
    for (int i = 0; i < 32; ++i) wreg[i] = wp[i];

    float c = (tid < 16) ? c0[wg * 16 + tid] : 0.f;
    {
        float2 h2 = *(const float2*)&h0[tid * 2];
        hbuf[tid * 2]     = h2.x;
        hbuf[tid * 2 + 1] = h2.y;
    }
    __syncthreads();

    for (int t = 0; t < TLEN; ++t) {
        const bool uf = (s_usefast != 0);

        // activation lanes' Xg (4 gate rows each), issued before the poll
        float xg0 = 0.f, xg1 = 0.f, xg2 = 0.f, xg3 = 0.f;
        if (tid < 16) {
            const float* xp = Xg + (size_t)t * G4 + wg * 16 + tid;
            xg0 = xp[0]; xg1 = xp[512]; xg2 = xp[1024]; xg3 = xp[1536];
        }

        if (t > 0) {
            const size_t off = (size_t)(t & 1) * HID + 2 * tid;
            u64 w0 = 0, w1 = 0;
            bool ok0 = false, ok1 = false, fok = false;

            if (uf) {                                   // bounded fast phase (XCD L2)
                const int K = (t == 1) ? 24 : 6;
                u64 fa = (u64)(uintptr_t)(pf + off);
                for (int it = 0; it < K; ++it) {
                    uivec4 pr;
                    asm volatile("global_load_dwordx4 %0, %1, off sc0\n\t"
                                 "s_waitcnt vmcnt(0)"
                                 : "=v"(pr) : "v"(fa));
                    if (!ok0 && pr.y == (unsigned)t) { w0 = ((u64)pr.y << 32) | pr.x; ok0 = true; }
                    if (!ok1 && pr.w == (unsigned)t) { w1 = ((u64)pr.w << 32) | pr.z; ok1 = true; }
                    if (ok0 && ok1) break;
                }
                fok = ok0 && ok1;
            }
            if (!(ok0 && ok1)) {                        // guaranteed MALL path
                u64 sa = (u64)(uintptr_t)(pk + off);
                do {
                    uivec4 pr;
                    asm volatile("global_load_dwordx4 %0, %1, off sc0 sc1\n\t"
                                 "s_waitcnt vmcnt(0)"
                                 : "=v"(pr) : "v"(sa));
                    if (!ok0 && pr.y == (unsigned)t) { w0 = ((u64)pr.y << 32) | pr.x; ok0 = true; }
                    if (!ok1 && pr.w == (unsigned)t) { w1 = ((u64)pr.w << 32) | pr.z; ok1 = true; }
                } while (!(ok0 && ok1));
            }
            if (t == 1 && intraflag) {                  // one-time transport vote
                u64 b = __ballot(fok ? 1 : 0);
                if ((tid & 63) == 0) svote[tid >> 6] = (b == ~0ull) ? 1 : 0;
            }
            hbuf[2 * tid]     = __uint_as_float((unsigned)w0);
            hbuf[2 * tid + 1] = __uint_as_float((unsigned)w1);
            __syncthreads();                            // B1
            if (t == 1 && intraflag && tid == 0)
                s_usefast = svote[0] & svote[1] & svote[2] & svote[3];
        }

        // partial matvec (hbuf reads are full-wave broadcasts: conflict-free)
        float acc8[8];
#pragma unroll
        for (int i = 0; i < 8; ++i) acc8[i] = 0.f;
#pragma unroll
        for (int i = 0; i < 32; ++i) {
            float4 w4 = wreg[i];
            float4 h4 = *(const float4*)&hbuf[wv * 128 + i * 4];
            acc8[i & 7] = fmaf(w4.x, h4.x, fmaf(w4.y, h4.y,
                          fmaf(w4.z, h4.z, fmaf(w4.w, h4.w, acc8[i & 7]))));
        }
        pbuf[tid] = ((acc8[0] + acc8[1]) + (acc8[2] + acc8[3]))
                  + ((acc8[4] + acc8[5]) + (acc8[6] + acc8[7]));
        __syncthreads();                                // B2

        if (tid < 16) {
            float gi = pbuf[tid]      + pbuf[64 + tid]  + pbuf[128 + tid] + pbuf[192 + tid] + xg0;
            float gf = pbuf[16 + tid] + pbuf[80 + tid]  + pbuf[144 + tid] + pbuf[208 + tid] + xg1;
            float gg = pbuf[32 + tid] + pbuf[96 + tid]  + pbuf[160 + tid] + pbuf[224 + tid] + xg2;
            float go = pbuf[48 + tid] + pbuf[112 + tid] + pbuf[176 + tid] + pbuf[240 + tid] + xg3;
            float i_ = fsig(gi);
            float f_ = fsig(gf);
            float g_ = ftanh(gg);
            float o_ = fsig(go);
            c = fmaf(f_, c, i_ * g_);
            float h_ = o_ * ftanh(c);
            hs[(size_t)t * HID + wg * 16 + tid] = h_;
            if (t < TLEN - 1) {
                u64 word = ((u64)(unsigned)(t + 1) << 32) | (u64)__float_as_uint(h_);
                size_t po = (size_t)((t + 1) & 1) * HID + wg * 16 + tid;
                __hip_atomic_store(&pk[po], word, __ATOMIC_RELAXED, __HIP_MEMORY_SCOPE_AGENT);
                if (intraflag) {
                    u64 faddr = (u64)(uintptr_t)(pf + po);
                    asm volatile("global_store_dwordx2 %0, %1, off sc0"
                                 :: "v"(faddr), "v"(word) : "memory");
                }
            } else {
                out_hT[wg * 16 + tid] = h_;
                out_cT[wg * 16 + tid] = c;
            }
        }
        // pbuf reads (act lanes) finish before those lanes reach next B1;
        // pbuf is rewritten only after next B1 -> safe with 2 barriers.
    }
}

// ---------------------------------------------------------------------------
// Kernel C: out[t][v] = hs[t] . W_out[v] + b_out[v]   (fp32, B^T input)
// 128x128 tile, BK=32, 8x8 register tile, 256 threads, grid (5, 250). Proven.
// ---------------------------------------------------------------------------
#define BM 128
#define BN 128
#define BK 32
#define LDT (BK + 4)   // 36: float4-aligned pad

__global__ __launch_bounds__(256) void out_gemm(
    const float* __restrict__ hs, const float* __restrict__ W_out,
    const float* __restrict__ b_out, float* __restrict__ out)
{
    __shared__ __align__(16) float As[BM][LDT];
    __shared__ __align__(16) float Bs[BN][LDT];

    const int tb = blockIdx.x;     // 0..4   (time tiles; fast dim)
    const int vb = blockIdx.y;     // 0..249 (vocab tiles)
    const int tid = threadIdx.x;
    const int tx = tid & 15;       // n group
    const int ty = tid >> 4;       // m group

    const int m0 = tb * BM, n0 = vb * BN;
    float acc[8][8];
#pragma unroll
    for (int i = 0; i < 8; ++i)
#pragma unroll
        for (int jj = 0; jj < 8; ++jj) acc[i][jj] = 0.f;

    for (int k0 = 0; k0 < HID; k0 += BK) {
#pragma unroll
        for (int it = 0; it < 4; ++it) {
            int li = tid + it * 256;        // 0..1023
            int m  = li >> 3;               // row 0..127
            int kq = li & 7;                // float4 index within BK
            int t  = m0 + m;
            float4 fa = (t < TLEN) ? *(const float4*)&hs[(size_t)t * HID + k0 + kq * 4]
                                   : make_float4(0.f, 0.f, 0.f, 0.f);
            *(float4*)&As[m][kq * 4] = fa;
            float4 fb = *(const float4*)&W_out[(size_t)(n0 + m) * HID + k0 + kq * 4];
            *(float4*)&Bs[m][kq * 4] = fb;
        }
        __syncthreads();

#pragma unroll
        for (int k4 = 0; k4 < BK / 4; ++k4) {
            float4 a4[8], b4[8];
#pragma unroll
            for (int i = 0; i < 8; ++i) a4[i] = *(const float4*)&As[ty + 16 * i][k4 * 4];
#pragma unroll
            for (int jj = 0; jj < 8; ++jj) b4[jj] = *(const float4*)&Bs[tx + 16 * jj][k4 * 4];
#pragma unroll
            for (int i = 0; i < 8; ++i)
#pragma unroll
                for (int jj = 0; jj < 8; ++jj) {
                    acc[i][jj] = fmaf(a4[i].x, b4[jj].x,
                                 fmaf(a4[i].y, b4[jj].y,
                                 fmaf(a4[i].z, b4[jj].z,
                                 fmaf(a4[i].w, b4[jj].w, acc[i][jj]))));
                }
        }
        __syncthreads();
    }

#pragma unroll
    for (int jj = 0; jj < 8; ++jj) {
        int v = n0 + tx + 16 * jj;
        float bo = b_out[v];
#pragma unroll
        for (int i = 0; i < 8; ++i) {
            int t = m0 + ty + 16 * i;
            if (t < TLEN) out[(size_t)t * VOCAB + v] = acc[i][jj] + bo;
        }
    }
}

// ---------------------------------------------------------------------------
extern "C" void kernel_launch(void* const* d_in, const int* in_sizes, int n_in,
                              void* d_out, int out_size, void* d_ws, size_t ws_size,
                              hipStream_t stream)
{
    const int*   seq   = (const int*)  d_in[0];
    const float* h0    = (const float*)d_in[1];
    const float* c0    = (const float*)d_in[2];
    const float* emb   = (const float*)d_in[3];
    const float* W_ih  = (const float*)d_in[4];
    const float* W_hh  = (const float*)d_in[5];
    const float* b_ih  = (const float*)d_in[6];
    const float* b_hh  = (const float*)d_in[7];
    const float* W_out = (const float*)d_in[8];
    const float* b_out = (const float*)d_in[9];

    float* out_logits = (float*)d_out;                      // [513][32000]
    float* out_hT     = out_logits + (size_t)TLEN * VOCAB;  // [512]
    float* out_cT     = out_hT + HID;                       // [512]

    float* Xg    = (float*)d_ws;                      // 513*2048 f
    float* hs    = Xg + (size_t)TLEN * G4;            // 513*512 f
    u64*   pk    = (u64*)(hs + (size_t)TLEN * HID);   // [2][512] slow (MALL) words
    u64*   pf    = pk + 2 * HID;                      // [2][512] fast (L2) words
    u64*   xrole = pf + 2 * HID;                      // [32] role->xcc table
    int*   ctrs  = (int*)(xrole + NWG);               // [8] claim counters

    size_t zbytes = (4 * HID + NWG) * sizeof(u64) + 8 * sizeof(int);
    hipMemsetAsync(pk, 0, zbytes, stream);
    precompute_gates<<<dim3(33, 8), 256, 0, stream>>>(seq, emb, W_ih, b_ih, b_hh, Xg);
    lstm_recurrence<<<GRID_LSTM, 256, 0, stream>>>(Xg, W_hh, h0, c0, hs, pk, pf, xrole, ctrs,
                                                   out_hT, out_cT);
    out_gemm<<<dim3(5, 250), 256, 0, stream>>>(hs, W_out, b_out, out_logits);
}